// Round 1
// baseline (109.317 us; speedup 1.0000x reference)
//
#include <hip/hip_runtime.h>
#include <hip/hip_bf16.h>

// out[i] = ((x[i] + 10) * 2)^2, fp32, 8192*8192 elements.
// Memory-bound: 512 MiB HBM traffic, target ~6.3 TB/s => ~85 us.

__global__ __launch_bounds__(256) void fused_elem_kernel(const float* __restrict__ x,
                                                         float* __restrict__ out,
                                                         long long n4) {
    const float4* __restrict__ x4 = reinterpret_cast<const float4*>(x);
    float4* __restrict__ o4 = reinterpret_cast<float4*>(out);
    long long stride = (long long)gridDim.x * blockDim.x;
    for (long long i = (long long)blockIdx.x * blockDim.x + threadIdx.x; i < n4; i += stride) {
        float4 v = x4[i];
        float a = (v.x + 10.0f) * 2.0f;
        float b = (v.y + 10.0f) * 2.0f;
        float c = (v.z + 10.0f) * 2.0f;
        float d = (v.w + 10.0f) * 2.0f;
        float4 r;
        r.x = a * a;
        r.y = b * b;
        r.z = c * c;
        r.w = d * d;
        o4[i] = r;
    }
}

__global__ __launch_bounds__(256) void fused_elem_tail(const float* __restrict__ x,
                                                       float* __restrict__ out,
                                                       long long start, long long n) {
    long long i = start + (long long)blockIdx.x * blockDim.x + threadIdx.x;
    if (i < n) {
        float a = (x[i] + 10.0f) * 2.0f;
        out[i] = a * a;
    }
}

extern "C" void kernel_launch(void* const* d_in, const int* in_sizes, int n_in,
                              void* d_out, int out_size, void* d_ws, size_t ws_size,
                              hipStream_t stream) {
    const float* x = (const float*)d_in[0];
    float* out = (float*)d_out;
    long long n = (long long)out_size;   // 8192*8192
    long long n4 = n / 4;

    const int block = 256;
    int grid = (int)((n4 + block - 1) / block);
    if (grid > 2048) grid = 2048;
    if (grid > 0) {
        fused_elem_kernel<<<grid, block, 0, stream>>>(x, out, n4);
    }

    long long tail_start = n4 * 4;
    long long tail = n - tail_start;
    if (tail > 0) {
        int tgrid = (int)((tail + block - 1) / block);
        fused_elem_tail<<<tgrid, block, 0, stream>>>(x, out, tail_start, n);
    }
}

// Round 3
// 88.683 us; speedup vs baseline: 1.2327x; 1.2327x over previous
//
#include <hip/hip_runtime.h>
#include <hip/hip_bf16.h>

// out[i] = ((x[i] + 10) * 2)^2, fp32, 8192*8192 elements.
// Memory-bound: 512 MiB HBM traffic. R1: 109.3 us (4.9 TB/s effective).
// R3: unroll x4 for MLP + nontemporal stores via native clang vector type
// (HIP float4 is a class -> builtin rejects it; ext_vector_type works).

typedef float fvec4 __attribute__((ext_vector_type(4)));

__global__ __launch_bounds__(256) void fused_elem_kernel(const fvec4* __restrict__ x4,
                                                         fvec4* __restrict__ o4,
                                                         long long n4) {
    const long long stride = (long long)gridDim.x * blockDim.x;
    long long i = (long long)blockIdx.x * blockDim.x + threadIdx.x;

    // Unrolled-by-4 main loop: 4 independent 16B loads in flight per wave.
    for (; i + 3 * stride < n4; i += 4 * stride) {
        fvec4 v0 = x4[i];
        fvec4 v1 = x4[i + stride];
        fvec4 v2 = x4[i + 2 * stride];
        fvec4 v3 = x4[i + 3 * stride];
        fvec4 t0 = (v0 + 10.0f) * 2.0f;
        fvec4 t1 = (v1 + 10.0f) * 2.0f;
        fvec4 t2 = (v2 + 10.0f) * 2.0f;
        fvec4 t3 = (v3 + 10.0f) * 2.0f;
        __builtin_nontemporal_store(t0 * t0, &o4[i]);
        __builtin_nontemporal_store(t1 * t1, &o4[i + stride]);
        __builtin_nontemporal_store(t2 * t2, &o4[i + 2 * stride]);
        __builtin_nontemporal_store(t3 * t3, &o4[i + 3 * stride]);
    }
    // Remainder (not taken for 8192^2, kept for generality).
    for (; i < n4; i += stride) {
        fvec4 v = x4[i];
        fvec4 t = (v + 10.0f) * 2.0f;
        __builtin_nontemporal_store(t * t, &o4[i]);
    }
}

__global__ __launch_bounds__(256) void fused_elem_tail(const float* __restrict__ x,
                                                       float* __restrict__ out,
                                                       long long start, long long n) {
    long long i = start + (long long)blockIdx.x * blockDim.x + threadIdx.x;
    if (i < n) {
        float a = (x[i] + 10.0f) * 2.0f;
        out[i] = a * a;
    }
}

extern "C" void kernel_launch(void* const* d_in, const int* in_sizes, int n_in,
                              void* d_out, int out_size, void* d_ws, size_t ws_size,
                              hipStream_t stream) {
    const float* x = (const float*)d_in[0];
    float* out = (float*)d_out;
    long long n = (long long)out_size;   // 8192*8192
    long long n4 = n / 4;

    const int block = 256;
    long long grid_ll = (n4 + block - 1) / block;
    int grid = grid_ll > 2048 ? 2048 : (int)grid_ll;
    if (grid > 0) {
        fused_elem_kernel<<<grid, block, 0, stream>>>(
            reinterpret_cast<const fvec4*>(x),
            reinterpret_cast<fvec4*>(out), n4);
    }

    long long tail_start = n4 * 4;
    long long tail = n - tail_start;
    if (tail > 0) {
        int tgrid = (int)((tail + block - 1) / block);
        fused_elem_tail<<<tgrid, block, 0, stream>>>(x, out, tail_start, n);
    }
}